// Round 10
// baseline (412.254 us; speedup 1.0000x reference)
//
#include <hip/hip_runtime.h>
#include <hip/hip_bf16.h>

#define NN 100000
#define NE 800000
#define INC 64
#define HID 128
#define KC 9
#define NB 98  // ceil(NN/1024) scan blocks

// glob layout (floats): x_pool[1152] | out_adj[81] | ss[81] | den[1]  => 1315
#define G_XP 0
#define G_OA 1152
#define G_SS 1233
#define G_DEN 1314

__device__ __forceinline__ float atomAddG(float* p, float v) {
  return unsafeAtomicAdd(p, v);  // HW global_atomic_add_f32
}

// ---- CSR build: histogram -> bsum -> write(scan fused) -> fill ---------

__global__ __launch_bounds__(256) void k_deg(const int* __restrict__ dst, int* __restrict__ degi) {
  int i = blockIdx.x * blockDim.x + threadIdx.x;
  int stride = gridDim.x * blockDim.x;
  for (; i < NE; i += stride) atomicAdd(&degi[dst[i]], 1);
}

__global__ __launch_bounds__(256) void k_bsum(const int* __restrict__ degi, int* __restrict__ bsum) {
  int t = threadIdx.x;
  int base = blockIdx.x * 1024 + t * 4;
  int d0 = 0, d1 = 0, d2 = 0, d3 = 0;
  if (base + 3 < NN) {
    int4 v = *(const int4*)(degi + base);
    d0 = v.x; d1 = v.y; d2 = v.z; d3 = v.w;
  } else {
    if (base < NN) d0 = degi[base];
    if (base + 1 < NN) d1 = degi[base + 1];
    if (base + 2 < NN) d2 = degi[base + 2];
  }
  int s = d0 + d1 + d2 + d3;
#pragma unroll
  for (int off = 32; off > 0; off >>= 1) s += __shfl_xor(s, off, 64);
  __shared__ int ws[4];
  if ((t & 63) == 0) ws[t >> 6] = s;
  __syncthreads();
  if (t == 0) bsum[blockIdx.x] = ws[0] + ws[1] + ws[2] + ws[3];
}

// k_write: each block redundantly scans bsum[98] in LDS, then block-local scan.
__global__ __launch_bounds__(256) void k_write(const int* __restrict__ degi, const int* __restrict__ bsum,
                                               int* __restrict__ rowptr, int* __restrict__ cursor,
                                               float* __restrict__ dinv) {
  int t = threadIdx.x;
  __shared__ int bsc[128];
  if (t < 128) bsc[t] = (t < NB) ? bsum[t] : 0;
  __syncthreads();
  for (int off = 1; off < 128; off <<= 1) {
    int u = (t < 128 && t >= off) ? bsc[t - off] : 0;
    __syncthreads();
    if (t < 128) bsc[t] += u;
    __syncthreads();
  }
  int boff_b = (blockIdx.x == 0) ? 0 : bsc[blockIdx.x - 1];  // exclusive block offset

  int base = blockIdx.x * 1024 + t * 4;
  int d0 = 0, d1 = 0, d2 = 0, d3 = 0;
  bool full = (base + 3 < NN);
  if (full) {
    int4 v = *(const int4*)(degi + base);
    d0 = v.x; d1 = v.y; d2 = v.z; d3 = v.w;
  } else {
    if (base < NN) d0 = degi[base];
    if (base + 1 < NN) d1 = degi[base + 1];
    if (base + 2 < NN) d2 = degi[base + 2];
  }
  int tsum = d0 + d1 + d2 + d3;
  __shared__ int sc[256];
  sc[t] = tsum;
  __syncthreads();
  for (int off = 1; off < 256; off <<= 1) {
    int u = (t >= off) ? sc[t - off] : 0;
    __syncthreads();
    sc[t] += u;
    __syncthreads();
  }
  int ex = sc[t] - tsum + boff_b;
  int r0 = ex, r1 = ex + d0, r2 = r1 + d1, r3 = r2 + d2;
  if (full) {
    int4 rv = make_int4(r0, r1, r2, r3);
    *(int4*)(rowptr + base) = rv;
    *(int4*)(cursor + base) = rv;
    float4 dv = make_float4(rsqrtf((float)d0 + 1.f), rsqrtf((float)d1 + 1.f),
                            rsqrtf((float)d2 + 1.f), rsqrtf((float)d3 + 1.f));
    *(float4*)(dinv + base) = dv;
  } else {
    if (base < NN) { rowptr[base] = r0; cursor[base] = r0; dinv[base] = rsqrtf((float)d0 + 1.f); }
    if (base + 1 < NN) { rowptr[base + 1] = r1; cursor[base + 1] = r1; dinv[base + 1] = rsqrtf((float)d1 + 1.f); }
    if (base + 2 < NN) { rowptr[base + 2] = r2; cursor[base + 2] = r2; dinv[base + 2] = rsqrtf((float)d2 + 1.f); }
  }
}

__global__ __launch_bounds__(256) void k_fill(const int* __restrict__ src, const int* __restrict__ dst,
                                              int* __restrict__ cursor, int* __restrict__ csr) {
  int i = blockIdx.x * blockDim.x + threadIdx.x;
  int stride = gridDim.x * blockDim.x;
  for (; i < NE; i += stride) {
    int p = atomicAdd(&cursor[dst[i]], 1);
    csr[p] = src[i];
  }
}

// ---- pure gather: agg = A_hat x  (4 nodes/wave, 16 lanes/node, x8 unroll)

__global__ __launch_bounds__(256) void k_gather(const int* __restrict__ rowptr, const int* __restrict__ degi,
                                                const int* __restrict__ csr, const float* __restrict__ x,
                                                const float* __restrict__ dinv, float* __restrict__ agg) {
  int t = threadIdx.x;
  int wave = t >> 6, lane = t & 63;
  int gw = blockIdx.x * 4 + wave;
  int ng = lane >> 4, c4 = lane & 15;
  int node = gw * 4 + ng;
  if (node >= NN) return;

  float dv = dinv[node];
  int base = rowptr[node];
  int cnt = degi[node];

  float4 xs = ((const float4*)(x + (size_t)node * INC))[c4];
  float dv2 = dv * dv;
  float4 acc;
  acc.x = dv2 * xs.x; acc.y = dv2 * xs.y; acc.z = dv2 * xs.z; acc.w = dv2 * xs.w;

  int j = 0;
  for (; j + 7 < cnt; j += 8) {
    int si[8];
    float w[8];
    float4 r[8];
#pragma unroll
    for (int u = 0; u < 8; ++u) si[u] = csr[base + j + u];
#pragma unroll
    for (int u = 0; u < 8; ++u) w[u] = dinv[si[u]] * dv;
#pragma unroll
    for (int u = 0; u < 8; ++u) r[u] = ((const float4*)(x + (size_t)si[u] * INC))[c4];
#pragma unroll
    for (int u = 0; u < 8; ++u) {
      acc.x = fmaf(w[u], r[u].x, acc.x); acc.y = fmaf(w[u], r[u].y, acc.y);
      acc.z = fmaf(w[u], r[u].z, acc.z); acc.w = fmaf(w[u], r[u].w, acc.w);
    }
  }
  for (; j < cnt; ++j) {
    int si = csr[base + j];
    float w = dinv[si] * dv;
    float4 r = ((const float4*)(x + (size_t)si * INC))[c4];
    acc.x = fmaf(w, r.x, acc.x); acc.y = fmaf(w, r.y, acc.y);
    acc.z = fmaf(w, r.z, acc.z); acc.w = fmaf(w, r.w, acc.w);
  }
  ((float4*)(agg + (size_t)node * INC))[c4] = acc;
}

// ---- MLP A: 2 nodes/thread, NO LDS. Weights read directly from global with
// wave-uniform constant indices -> compiler emits s_load (SMEM pipe, SGPR
// broadcast, free FMA operand). DS pipe completely idle; VALU-bound.

__global__ __launch_bounds__(256) void k_mlpA(const float* __restrict__ agg,
                                              const float* __restrict__ W1, const float* __restrict__ b1,
                                              const float* __restrict__ Wp, const float* __restrict__ bp,
                                              float* __restrict__ s_out, float* __restrict__ s_pad,
                                              float* __restrict__ h_glob) {
  int t = threadIdx.x;
  int node0 = blockIdx.x * 256 + t;      // [0, 65536)
  int node1 = node0 + 65536;             // [65536, 131072)
  bool v1 = (node1 < NN);

  float a0[INC], a1[INC];
  {
    const float4* ar0 = (const float4*)(agg + (size_t)node0 * INC);
#pragma unroll
    for (int i = 0; i < 16; ++i) {
      float4 v = ar0[i];
      a0[4 * i + 0] = v.x; a0[4 * i + 1] = v.y; a0[4 * i + 2] = v.z; a0[4 * i + 3] = v.w;
    }
    if (v1) {
      const float4* ar1 = (const float4*)(agg + (size_t)node1 * INC);
#pragma unroll
      for (int i = 0; i < 16; ++i) {
        float4 v = ar1[i];
        a1[4 * i + 0] = v.x; a1[4 * i + 1] = v.y; a1[4 * i + 2] = v.z; a1[4 * i + 3] = v.w;
      }
    } else {
#pragma unroll
      for (int i = 0; i < INC; ++i) a1[i] = 0.f;
    }
  }

  float lg0[KC], lg1[KC];
#pragma unroll
  for (int q = 0; q < KC; ++q) { float b = bp[q]; lg0[q] = b; lg1[q] = b; }  // uniform -> s_load

  float4* hout0 = (float4*)(h_glob + (size_t)node0 * HID);
  float4* hout1 = (float4*)(h_glob + (size_t)node1 * HID);

#pragma unroll 1
  for (int ch = 0; ch < 8; ++ch) {    // 8 chunks x 16 cols
    float h0c[16], h1c[16];
#pragma unroll
    for (int i = 0; i < 16; ++i) {
      float b = b1[ch * 16 + i];       // uniform -> s_load
      h0c[i] = b; h1c[i] = b;
    }
#pragma unroll
    for (int k = 0; k < INC; ++k) {
      const float* wr = &W1[k * HID + ch * 16];  // uniform base, const offsets
      float ak0 = a0[k], ak1 = a1[k];
#pragma unroll
      for (int i = 0; i < 16; ++i) {
        float w = wr[i];               // uniform -> s_load (SGPR operand)
        h0c[i] = fmaf(ak0, w, h0c[i]);
        h1c[i] = fmaf(ak1, w, h1c[i]);
      }
    }
    // relu + logit accumulation (uniform Wp -> s_load)
#pragma unroll
    for (int i = 0; i < 16; ++i) {
      float hr0 = fmaxf(h0c[i], 0.f); h0c[i] = hr0;
      float hr1 = fmaxf(h1c[i], 0.f); h1c[i] = hr1;
      const float* wp = &Wp[(ch * 16 + i) * KC];
#pragma unroll
      for (int q = 0; q < KC; ++q) {
        float w = wp[q];
        lg0[q] = fmaf(hr0, w, lg0[q]);
        lg1[q] = fmaf(hr1, w, lg1[q]);
      }
    }
#pragma unroll
    for (int i = 0; i < 4; ++i)
      hout0[ch * 4 + i] = make_float4(h0c[4 * i], h0c[4 * i + 1], h0c[4 * i + 2], h0c[4 * i + 3]);
    if (v1) {
#pragma unroll
      for (int i = 0; i < 4; ++i)
        hout1[ch * 4 + i] = make_float4(h1c[4 * i], h1c[4 * i + 1], h1c[4 * i + 2], h1c[4 * i + 3]);
    }
  }

  {
    float m = lg0[0];
#pragma unroll
    for (int q = 1; q < KC; ++q) m = fmaxf(m, lg0[q]);
    float Z = 0.f;
#pragma unroll
    for (int q = 0; q < KC; ++q) { lg0[q] = __expf(lg0[q] - m); Z += lg0[q]; }
    float inv = 1.0f / Z;
#pragma unroll
    for (int q = 0; q < KC; ++q) lg0[q] *= inv;
    float* so = s_out + (size_t)node0 * KC;
#pragma unroll
    for (int q = 0; q < KC; ++q) so[q] = lg0[q];
    float4* sp = (float4*)(s_pad + (size_t)node0 * 12);
    sp[0] = make_float4(lg0[0], lg0[1], lg0[2], lg0[3]);
    sp[1] = make_float4(lg0[4], lg0[5], lg0[6], lg0[7]);
    sp[2] = make_float4(lg0[8], 0.f, 0.f, 0.f);
  }
  if (v1) {
    float m = lg1[0];
#pragma unroll
    for (int q = 1; q < KC; ++q) m = fmaxf(m, lg1[q]);
    float Z = 0.f;
#pragma unroll
    for (int q = 0; q < KC; ++q) { lg1[q] = __expf(lg1[q] - m); Z += lg1[q]; }
    float inv = 1.0f / Z;
#pragma unroll
    for (int q = 0; q < KC; ++q) lg1[q] *= inv;
    float* so = s_out + (size_t)node1 * KC;
#pragma unroll
    for (int q = 0; q < KC; ++q) so[q] = lg1[q];
    float4* sp = (float4*)(s_pad + (size_t)node1 * 12);
    sp[0] = make_float4(lg1[0], lg1[1], lg1[2], lg1[3]);
    sp[1] = make_float4(lg1[4], lg1[5], lg1[6], lg1[7]);
    sp[2] = make_float4(lg1[8], 0.f, 0.f, 0.f);
  }
}

// ---- fused post: phase1 pool (x_pool, ss, den), phase2 out_adj ---------

__global__ __launch_bounds__(256) void k_post(const float* __restrict__ h_glob,
                                              const float* __restrict__ s_pad,
                                              const int* __restrict__ degi,
                                              const int* __restrict__ rowptr,
                                              const int* __restrict__ csr,
                                              float* __restrict__ glob) {
  int t = threadIdx.x;
  int wave = t >> 6, lane = t & 63;
  __shared__ float smem[KC * HID + 82];

  // ---------- phase 1: pool ----------
  {
    int gw = blockIdx.x * 4 + wave;
    int nw = gridDim.x * 4;
    const int c0 = 2 * lane;

    float pool0[KC], pool1[KC], ssr[KC];
    float den_acc = 0.f;
#pragma unroll
    for (int q = 0; q < KC; ++q) { pool0[q] = 0.f; pool1[q] = 0.f; ssr[q] = 0.f; }

    for (int node0 = gw; node0 < NN; node0 += nw) {
      int node = __builtin_amdgcn_readfirstlane(node0);
      float2 hv = *(const float2*)&h_glob[(size_t)node * HID + c0];  // coalesced
      const float* srow = s_pad + (size_t)node * 12;
      float4 s0 = *(const float4*)srow;
      float4 s1 = *(const float4*)(srow + 4);
      float s8 = srow[8];
      float sb[KC] = {s0.x, s0.y, s0.z, s0.w, s1.x, s1.y, s1.z, s1.w, s8};
      float sq = (lane < KC) ? srow[lane] : 0.f;
      float dg = (float)degi[node];

#pragma unroll
      for (int q = 0; q < KC; ++q) {
        pool0[q] = fmaf(sb[q], hv.x, pool0[q]);
        pool1[q] = fmaf(sb[q], hv.y, pool1[q]);
      }
      if (lane < KC) {
#pragma unroll
        for (int q = 0; q < KC; ++q) ssr[q] = fmaf(sq, sb[q], ssr[q]);
        den_acc = fmaf(dg * sq, sq, den_acc);
      }
    }

    float* pool_sh = smem;
    float* ss_sh = smem + KC * HID;
    float* den_sh = ss_sh + 81;
    for (int i = t; i < KC * HID + 82; i += 256) smem[i] = 0.f;
    __syncthreads();

#pragma unroll
    for (int q = 0; q < KC; ++q) {
      atomicAdd(&pool_sh[q * HID + c0], pool0[q]);
      atomicAdd(&pool_sh[q * HID + c0 + 1], pool1[q]);
    }
    if (lane < KC) {
#pragma unroll
      for (int q = 0; q < KC; ++q) atomicAdd(&ss_sh[lane * KC + q], ssr[q]);
      atomicAdd(den_sh, den_acc);
    }
    __syncthreads();

    for (int i = t; i < KC * HID; i += 256) atomAddG(&glob[G_XP + i], pool_sh[i]);
    if (t < KC * KC) atomAddG(&glob[G_SS + t], ss_sh[t]);
    if (t == 0) atomAddG(&glob[G_DEN], *den_sh);
    __syncthreads();  // smem reused below
  }

  // ---------- phase 2: out_adj ----------
  {
    float acc[81];
#pragma unroll
    for (int i = 0; i < 81; ++i) acc[i] = 0.f;

    int node = blockIdx.x * blockDim.x + t;
    if (node < NN) {
      int base = rowptr[node];
      int cnt = degi[node];
      float4 g0 = make_float4(0.f, 0.f, 0.f, 0.f);
      float4 g1 = g0;
      float g8 = 0.f;
      int j = 0;
      for (; j + 3 < cnt; j += 4) {
        int si[4];
#pragma unroll
        for (int u = 0; u < 4; ++u) si[u] = csr[base + j + u];
        float4 a[4], b[4], c[4];
#pragma unroll
        for (int u = 0; u < 4; ++u) {
          const float4* p = (const float4*)(s_pad + (size_t)si[u] * 12);
          a[u] = p[0]; b[u] = p[1]; c[u] = p[2];
        }
#pragma unroll
        for (int u = 0; u < 4; ++u) {
          g0.x += a[u].x; g0.y += a[u].y; g0.z += a[u].z; g0.w += a[u].w;
          g1.x += b[u].x; g1.y += b[u].y; g1.z += b[u].z; g1.w += b[u].w;
          g8 += c[u].x;
        }
      }
      for (; j < cnt; ++j) {
        int s0 = csr[base + j];
        const float4* p0 = (const float4*)(s_pad + (size_t)s0 * 12);
        float4 a0 = p0[0], b0 = p0[1], c0 = p0[2];
        g0.x += a0.x; g0.y += a0.y; g0.z += a0.z; g0.w += a0.w;
        g1.x += b0.x; g1.y += b0.y; g1.z += b0.z; g1.w += b0.w;
        g8 += c0.x;
      }
      const float4* sn = (const float4*)(s_pad + (size_t)node * 12);
      float4 d0 = sn[0], d1 = sn[1], d2 = sn[2];
      float gg[9] = {g0.x, g0.y, g0.z, g0.w, g1.x, g1.y, g1.z, g1.w, g8};
      float sd[9] = {d0.x, d0.y, d0.z, d0.w, d1.x, d1.y, d1.z, d1.w, d2.x};
#pragma unroll
      for (int i = 0; i < 9; ++i)
#pragma unroll
        for (int jj = 0; jj < 9; ++jj) acc[i * 9 + jj] = fmaf(gg[i], sd[jj], acc[i * 9 + jj]);
    }

#pragma unroll
    for (int i = 0; i < 81; ++i) {
#pragma unroll
      for (int off = 32; off > 0; off >>= 1) acc[i] += __shfl_xor(acc[i], off, 64);
    }
    float* wsum = smem;  // reuse, 4*81 floats
    if (lane == 0) {
#pragma unroll
      for (int i = 0; i < 81; ++i) wsum[wave * 81 + i] = acc[i];
    }
    __syncthreads();
    if (t < 81) atomAddG(&glob[G_OA + t], wsum[t] + wsum[81 + t] + wsum[162 + t] + wsum[243 + t]);
  }
}

// ---- epilogue ----------------------------------------------------------

__global__ __launch_bounds__(128) void k_final(const float* __restrict__ glob, float* __restrict__ out) {
  const float* xp = glob + G_XP;
  const float* oa = glob + G_OA;
  const float* ssm = glob + G_SS;
  const float* den = glob + G_DEN;
  int t = threadIdx.x;
  __shared__ float red[128];

  for (int k = 0; k < 9; ++k) {
    float v = xp[k * 128 + t];
    red[t] = v;
    __syncthreads();
    for (int s2 = 64; s2 > 0; s2 >>= 1) {
      if (t < s2) red[t] = fmaxf(red[t], red[t + s2]);
      __syncthreads();
    }
    float m = red[0];
    __syncthreads();
    red[t] = expf(v - m);
    __syncthreads();
    for (int s2 = 64; s2 > 0; s2 >>= 1) {
      if (t < s2) red[t] += red[t + s2];
      __syncthreads();
    }
    float lz = logf(red[0]) + m;
    __syncthreads();
    out[k * 128 + t] = v - lz;
  }

  if (t == 0) {
    float num = 0.f;
    for (int q = 0; q < 9; ++q) num += oa[q * 9 + q];
    out[1152] = -(num / (den[0] + 1e-15f));

    float fn = 0.f;
    for (int i = 0; i < 81; ++i) fn += ssm[i] * ssm[i];
    float rfn = 1.0f / sqrtf(fn);
    float osum = 0.f;
    for (int i = 0; i < 9; ++i)
      for (int j = 0; j < 9; ++j) {
        float v = ssm[i * 9 + j] * rfn - ((i == j) ? (1.0f / 3.0f) : 0.f);
        osum += v * v;
      }
    out[1153] = sqrtf(osum);
  }

  __shared__ float dsh[9];
  if (t < 9) {
    float d = 0.f;
    for (int j = 0; j < 9; ++j)
      if (j != t) d += oa[t * 9 + j];
    dsh[t] = 1.0f / sqrtf(d + 1e-15f);
  }
  __syncthreads();
  if (t < 81) {
    int i = t / 9, j = t % 9;
    out[901154 + t] = (i == j) ? 0.f : dsh[i] * oa[t] * dsh[j];
  }
}

extern "C" void kernel_launch(void* const* d_in, const int* in_sizes, int n_in,
                              void* d_out, int out_size, void* d_ws, size_t ws_size,
                              hipStream_t stream) {
  const float* x = (const float*)d_in[0];
  const int* ei = (const int*)d_in[1];
  const float* W1 = (const float*)d_in[3];
  const float* b1 = (const float*)d_in[4];
  const float* Wp = (const float*)d_in[5];
  const float* bp = (const float*)d_in[6];
  float* out = (float*)d_out;

  // ws: deg_i[NN] | glob[1315] | rowptr[NN] | cursor[NN] | csr[NE] | dinv[NN] |
  //     s_pad[NN*12] | bsum[NB] | agg[NN*64] | h_glob[NN*128]
  int* deg_i = (int*)d_ws;
  float* glob = (float*)d_ws + NN;
  int* rowptr = (int*)d_ws + NN + 1315;
  int* cursor = rowptr + NN;
  int* csr = cursor + NN;
  float* dinv = (float*)(csr + NE);
  float* s_pad = dinv + NN;
  int* bsum = (int*)(s_pad + (size_t)NN * 12);
  float* agg = (float*)(bsum + NB + 2);
  float* h_glob = agg + (size_t)NN * INC;

  hipMemsetAsync(d_ws, 0, (size_t)(NN + 1315) * sizeof(float), stream);

  const int* src = ei;
  const int* dst = ei + NE;

  hipLaunchKernelGGL(k_deg, dim3(1024), dim3(256), 0, stream, dst, deg_i);
  hipLaunchKernelGGL(k_bsum, dim3(NB), dim3(256), 0, stream, deg_i, bsum);
  hipLaunchKernelGGL(k_write, dim3(NB), dim3(256), 0, stream, deg_i, bsum, rowptr, cursor, dinv);
  hipLaunchKernelGGL(k_fill, dim3(2048), dim3(256), 0, stream, src, dst, cursor, csr);
  hipLaunchKernelGGL(k_gather, dim3(6250), dim3(256), 0, stream, rowptr, deg_i, csr, x, dinv, agg);
  hipLaunchKernelGGL(k_mlpA, dim3(256), dim3(256), 0, stream, agg,
                     W1, b1, Wp, bp, out + 1154, s_pad, h_glob);
  hipLaunchKernelGGL(k_post, dim3(512), dim3(256), 0, stream, h_glob, s_pad, deg_i,
                     rowptr, csr, glob);
  hipLaunchKernelGGL(k_final, dim3(1), dim3(128), 0, stream, glob, out);
}

// Round 11
// 351.028 us; speedup vs baseline: 1.1744x; 1.1744x over previous
//
#include <hip/hip_runtime.h>
#include <hip/hip_bf16.h>

#define NN 100000
#define NE 800000
#define INC 64
#define HID 128
#define KC 9
#define NB 98  // ceil(NN/1024) scan blocks

// glob layout (floats): x_pool[1152] | out_adj[81] | ss[81] | den[1]  => 1315
#define G_XP 0
#define G_OA 1152
#define G_SS 1233
#define G_DEN 1314

__device__ __forceinline__ float atomAddG(float* p, float v) {
  return unsafeAtomicAdd(p, v);  // HW global_atomic_add_f32
}

// ---- CSR build: histogram -> bsum -> write(scan fused) -> fill ---------

__global__ __launch_bounds__(256) void k_deg(const int* __restrict__ dst, int* __restrict__ degi) {
  int i = blockIdx.x * blockDim.x + threadIdx.x;
  int stride = gridDim.x * blockDim.x;
  for (; i < NE; i += stride) atomicAdd(&degi[dst[i]], 1);
}

__global__ __launch_bounds__(256) void k_bsum(const int* __restrict__ degi, int* __restrict__ bsum) {
  int t = threadIdx.x;
  int base = blockIdx.x * 1024 + t * 4;
  int d0 = 0, d1 = 0, d2 = 0, d3 = 0;
  if (base + 3 < NN) {
    int4 v = *(const int4*)(degi + base);
    d0 = v.x; d1 = v.y; d2 = v.z; d3 = v.w;
  } else {
    if (base < NN) d0 = degi[base];
    if (base + 1 < NN) d1 = degi[base + 1];
    if (base + 2 < NN) d2 = degi[base + 2];
  }
  int s = d0 + d1 + d2 + d3;
#pragma unroll
  for (int off = 32; off > 0; off >>= 1) s += __shfl_xor(s, off, 64);
  __shared__ int ws[4];
  if ((t & 63) == 0) ws[t >> 6] = s;
  __syncthreads();
  if (t == 0) bsum[blockIdx.x] = ws[0] + ws[1] + ws[2] + ws[3];
}

// k_write: each block redundantly scans bsum[98] in LDS, then block-local scan.
__global__ __launch_bounds__(256) void k_write(const int* __restrict__ degi, const int* __restrict__ bsum,
                                               int* __restrict__ rowptr, int* __restrict__ cursor,
                                               float* __restrict__ dinv) {
  int t = threadIdx.x;
  __shared__ int bsc[128];
  if (t < 128) bsc[t] = (t < NB) ? bsum[t] : 0;
  __syncthreads();
  for (int off = 1; off < 128; off <<= 1) {
    int u = (t < 128 && t >= off) ? bsc[t - off] : 0;
    __syncthreads();
    if (t < 128) bsc[t] += u;
    __syncthreads();
  }
  int boff_b = (blockIdx.x == 0) ? 0 : bsc[blockIdx.x - 1];  // exclusive block offset

  int base = blockIdx.x * 1024 + t * 4;
  int d0 = 0, d1 = 0, d2 = 0, d3 = 0;
  bool full = (base + 3 < NN);
  if (full) {
    int4 v = *(const int4*)(degi + base);
    d0 = v.x; d1 = v.y; d2 = v.z; d3 = v.w;
  } else {
    if (base < NN) d0 = degi[base];
    if (base + 1 < NN) d1 = degi[base + 1];
    if (base + 2 < NN) d2 = degi[base + 2];
  }
  int tsum = d0 + d1 + d2 + d3;
  __shared__ int sc[256];
  sc[t] = tsum;
  __syncthreads();
  for (int off = 1; off < 256; off <<= 1) {
    int u = (t >= off) ? sc[t - off] : 0;
    __syncthreads();
    sc[t] += u;
    __syncthreads();
  }
  int ex = sc[t] - tsum + boff_b;
  int r0 = ex, r1 = ex + d0, r2 = r1 + d1, r3 = r2 + d2;
  if (full) {
    int4 rv = make_int4(r0, r1, r2, r3);
    *(int4*)(rowptr + base) = rv;
    *(int4*)(cursor + base) = rv;
    float4 dv = make_float4(rsqrtf((float)d0 + 1.f), rsqrtf((float)d1 + 1.f),
                            rsqrtf((float)d2 + 1.f), rsqrtf((float)d3 + 1.f));
    *(float4*)(dinv + base) = dv;
  } else {
    if (base < NN) { rowptr[base] = r0; cursor[base] = r0; dinv[base] = rsqrtf((float)d0 + 1.f); }
    if (base + 1 < NN) { rowptr[base + 1] = r1; cursor[base + 1] = r1; dinv[base + 1] = rsqrtf((float)d1 + 1.f); }
    if (base + 2 < NN) { rowptr[base + 2] = r2; cursor[base + 2] = r2; dinv[base + 2] = rsqrtf((float)d2 + 1.f); }
  }
}

__global__ __launch_bounds__(256) void k_fill(const int* __restrict__ src, const int* __restrict__ dst,
                                              int* __restrict__ cursor, int* __restrict__ csr) {
  int i = blockIdx.x * blockDim.x + threadIdx.x;
  int stride = gridDim.x * blockDim.x;
  for (; i < NE; i += stride) {
    int p = atomicAdd(&cursor[dst[i]], 1);
    csr[p] = src[i];
  }
}

// ---- pure gather: agg = A_hat x  (4 nodes/wave, 16 lanes/node, x8 unroll)

__global__ __launch_bounds__(256) void k_gather(const int* __restrict__ rowptr, const int* __restrict__ degi,
                                                const int* __restrict__ csr, const float* __restrict__ x,
                                                const float* __restrict__ dinv, float* __restrict__ agg) {
  int t = threadIdx.x;
  int wave = t >> 6, lane = t & 63;
  int gw = blockIdx.x * 4 + wave;
  int ng = lane >> 4, c4 = lane & 15;
  int node = gw * 4 + ng;
  if (node >= NN) return;

  float dv = dinv[node];
  int base = rowptr[node];
  int cnt = degi[node];

  float4 xs = ((const float4*)(x + (size_t)node * INC))[c4];
  float dv2 = dv * dv;
  float4 acc;
  acc.x = dv2 * xs.x; acc.y = dv2 * xs.y; acc.z = dv2 * xs.z; acc.w = dv2 * xs.w;

  int j = 0;
  for (; j + 7 < cnt; j += 8) {
    int si[8];
    float w[8];
    float4 r[8];
#pragma unroll
    for (int u = 0; u < 8; ++u) si[u] = csr[base + j + u];
#pragma unroll
    for (int u = 0; u < 8; ++u) w[u] = dinv[si[u]] * dv;
#pragma unroll
    for (int u = 0; u < 8; ++u) r[u] = ((const float4*)(x + (size_t)si[u] * INC))[c4];
#pragma unroll
    for (int u = 0; u < 8; ++u) {
      acc.x = fmaf(w[u], r[u].x, acc.x); acc.y = fmaf(w[u], r[u].y, acc.y);
      acc.z = fmaf(w[u], r[u].z, acc.z); acc.w = fmaf(w[u], r[u].w, acc.w);
    }
  }
  for (; j < cnt; ++j) {
    int si = csr[base + j];
    float w = dinv[si] * dv;
    float4 r = ((const float4*)(x + (size_t)si * INC))[c4];
    acc.x = fmaf(w, r.x, acc.x); acc.y = fmaf(w, r.y, acc.y);
    acc.z = fmaf(w, r.z, acc.z); acc.w = fmaf(w, r.w, acc.w);
  }
  ((float4*)(agg + (size_t)node * INC))[c4] = acc;
}

// ---- MLP A: 1 node/thread, broadcast-only LDS, chunked h (no scratch).
// block=128, grid=782 -> ~3 blocks/CU balanced (R7 had 391x256: half the CUs
// at 2 blocks set the runtime). VGPR ~64 so occupancy is LDS/grid-bound.

__global__ __launch_bounds__(128) void k_mlpA(const float* __restrict__ agg,
                                              const float* __restrict__ W1, const float* __restrict__ b1,
                                              const float* __restrict__ Wp, const float* __restrict__ bp,
                                              float* __restrict__ s_out, float* __restrict__ s_pad,
                                              float* __restrict__ h_glob) {
  __shared__ float W1s[INC * HID];   // 32 KB, row-major [k][c]
  __shared__ float Wps[HID * 12];    // 6 KB, rows padded to 12
  __shared__ float b1s[HID];

  int t = threadIdx.x;
  for (int i = t; i < (INC * HID) / 4; i += 128) ((float4*)W1s)[i] = ((const float4*)W1)[i];
  for (int i = t; i < HID * KC; i += 128) { int c = i / KC, q = i - c * KC; Wps[c * 12 + q] = Wp[i]; }
  b1s[t] = b1[t];  // t < 128 == HID
  __syncthreads();

  int node = blockIdx.x * 128 + t;
  if (node >= NN) return;

  // load own agg row into registers (constant indices -> full promotion)
  float a[INC];
  {
    const float4* arow = (const float4*)(agg + (size_t)node * INC);
#pragma unroll
    for (int i = 0; i < 16; ++i) {
      float4 v = arow[i];
      a[4 * i + 0] = v.x; a[4 * i + 1] = v.y; a[4 * i + 2] = v.z; a[4 * i + 3] = v.w;
    }
  }

  float logit[KC];
#pragma unroll
  for (int q = 0; q < KC; ++q) logit[q] = bp[q];  // uniform -> scalar load

  float4* hout = (float4*)(h_glob + (size_t)node * HID);

#pragma unroll 1
  for (int ch = 0; ch < 8; ++ch) {    // 8 chunks x 16 cols
    float h16[16];
    {
      const float4* bv = (const float4*)&b1s[ch * 16];
#pragma unroll
      for (int i = 0; i < 4; ++i) {
        float4 v = bv[i];  // broadcast
        h16[4 * i + 0] = v.x; h16[4 * i + 1] = v.y; h16[4 * i + 2] = v.z; h16[4 * i + 3] = v.w;
      }
    }
#pragma unroll
    for (int k = 0; k < INC; ++k) {
      const float4* wrow = (const float4*)&W1s[k * HID + ch * 16];
      float ak = a[k];
#pragma unroll
      for (int i = 0; i < 4; ++i) {
        float4 w = wrow[i];  // wave-uniform broadcast read
        h16[4 * i + 0] = fmaf(ak, w.x, h16[4 * i + 0]);
        h16[4 * i + 1] = fmaf(ak, w.y, h16[4 * i + 1]);
        h16[4 * i + 2] = fmaf(ak, w.z, h16[4 * i + 2]);
        h16[4 * i + 3] = fmaf(ak, w.w, h16[4 * i + 3]);
      }
    }
    // relu + logit accumulation (fully unrolled, constant indices)
#pragma unroll
    for (int i = 0; i < 16; ++i) {
      float hr = fmaxf(h16[i], 0.f);
      h16[i] = hr;
      const float4* wp = (const float4*)&Wps[(ch * 16 + i) * 12];
      float4 w0 = wp[0], w1 = wp[1], w2 = wp[2];  // broadcast
      logit[0] = fmaf(hr, w0.x, logit[0]);
      logit[1] = fmaf(hr, w0.y, logit[1]);
      logit[2] = fmaf(hr, w0.z, logit[2]);
      logit[3] = fmaf(hr, w0.w, logit[3]);
      logit[4] = fmaf(hr, w1.x, logit[4]);
      logit[5] = fmaf(hr, w1.y, logit[5]);
      logit[6] = fmaf(hr, w1.z, logit[6]);
      logit[7] = fmaf(hr, w1.w, logit[7]);
      logit[8] = fmaf(hr, w2.x, logit[8]);
    }
#pragma unroll
    for (int i = 0; i < 4; ++i)
      hout[ch * 4 + i] = make_float4(h16[4 * i], h16[4 * i + 1], h16[4 * i + 2], h16[4 * i + 3]);
  }

  // softmax (lane-local, no shuffles)
  float m = logit[0];
#pragma unroll
  for (int q = 1; q < KC; ++q) m = fmaxf(m, logit[q]);
  float Z = 0.f;
#pragma unroll
  for (int q = 0; q < KC; ++q) { logit[q] = __expf(logit[q] - m); Z += logit[q]; }
  float inv = 1.0f / Z;
#pragma unroll
  for (int q = 0; q < KC; ++q) logit[q] *= inv;

  float* so = s_out + (size_t)node * KC;
#pragma unroll
  for (int q = 0; q < KC; ++q) so[q] = logit[q];
  float4* sp = (float4*)(s_pad + (size_t)node * 12);
  sp[0] = make_float4(logit[0], logit[1], logit[2], logit[3]);
  sp[1] = make_float4(logit[4], logit[5], logit[6], logit[7]);
  sp[2] = make_float4(logit[8], 0.f, 0.f, 0.f);
}

// ---- fused post: phase1 pool (x_pool, ss, den), phase2 out_adj ---------

__global__ __launch_bounds__(256) void k_post(const float* __restrict__ h_glob,
                                              const float* __restrict__ s_pad,
                                              const int* __restrict__ degi,
                                              const int* __restrict__ rowptr,
                                              const int* __restrict__ csr,
                                              float* __restrict__ glob) {
  int t = threadIdx.x;
  int wave = t >> 6, lane = t & 63;
  __shared__ float smem[KC * HID + 82];

  // ---------- phase 1: pool ----------
  {
    int gw = blockIdx.x * 4 + wave;
    int nw = gridDim.x * 4;
    const int c0 = 2 * lane;

    float pool0[KC], pool1[KC], ssr[KC];
    float den_acc = 0.f;
#pragma unroll
    for (int q = 0; q < KC; ++q) { pool0[q] = 0.f; pool1[q] = 0.f; ssr[q] = 0.f; }

    for (int node0 = gw; node0 < NN; node0 += nw) {
      int node = __builtin_amdgcn_readfirstlane(node0);
      float2 hv = *(const float2*)&h_glob[(size_t)node * HID + c0];  // coalesced
      const float* srow = s_pad + (size_t)node * 12;
      float4 s0 = *(const float4*)srow;
      float4 s1 = *(const float4*)(srow + 4);
      float s8 = srow[8];
      float sb[KC] = {s0.x, s0.y, s0.z, s0.w, s1.x, s1.y, s1.z, s1.w, s8};
      float sq = (lane < KC) ? srow[lane] : 0.f;
      float dg = (float)degi[node];

#pragma unroll
      for (int q = 0; q < KC; ++q) {
        pool0[q] = fmaf(sb[q], hv.x, pool0[q]);
        pool1[q] = fmaf(sb[q], hv.y, pool1[q]);
      }
      if (lane < KC) {
#pragma unroll
        for (int q = 0; q < KC; ++q) ssr[q] = fmaf(sq, sb[q], ssr[q]);
        den_acc = fmaf(dg * sq, sq, den_acc);
      }
    }

    float* pool_sh = smem;
    float* ss_sh = smem + KC * HID;
    float* den_sh = ss_sh + 81;
    for (int i = t; i < KC * HID + 82; i += 256) smem[i] = 0.f;
    __syncthreads();

#pragma unroll
    for (int q = 0; q < KC; ++q) {
      atomicAdd(&pool_sh[q * HID + c0], pool0[q]);
      atomicAdd(&pool_sh[q * HID + c0 + 1], pool1[q]);
    }
    if (lane < KC) {
#pragma unroll
      for (int q = 0; q < KC; ++q) atomicAdd(&ss_sh[lane * KC + q], ssr[q]);
      atomicAdd(den_sh, den_acc);
    }
    __syncthreads();

    for (int i = t; i < KC * HID; i += 256) atomAddG(&glob[G_XP + i], pool_sh[i]);
    if (t < KC * KC) atomAddG(&glob[G_SS + t], ss_sh[t]);
    if (t == 0) atomAddG(&glob[G_DEN], *den_sh);
    __syncthreads();  // smem reused below
  }

  // ---------- phase 2: out_adj ----------
  {
    float acc[81];
#pragma unroll
    for (int i = 0; i < 81; ++i) acc[i] = 0.f;

    int node = blockIdx.x * blockDim.x + t;
    if (node < NN) {
      int base = rowptr[node];
      int cnt = degi[node];
      float4 g0 = make_float4(0.f, 0.f, 0.f, 0.f);
      float4 g1 = g0;
      float g8 = 0.f;
      int j = 0;
      for (; j + 3 < cnt; j += 4) {
        int si[4];
#pragma unroll
        for (int u = 0; u < 4; ++u) si[u] = csr[base + j + u];
        float4 a[4], b[4], c[4];
#pragma unroll
        for (int u = 0; u < 4; ++u) {
          const float4* p = (const float4*)(s_pad + (size_t)si[u] * 12);
          a[u] = p[0]; b[u] = p[1]; c[u] = p[2];
        }
#pragma unroll
        for (int u = 0; u < 4; ++u) {
          g0.x += a[u].x; g0.y += a[u].y; g0.z += a[u].z; g0.w += a[u].w;
          g1.x += b[u].x; g1.y += b[u].y; g1.z += b[u].z; g1.w += b[u].w;
          g8 += c[u].x;
        }
      }
      for (; j < cnt; ++j) {
        int s0 = csr[base + j];
        const float4* p0 = (const float4*)(s_pad + (size_t)s0 * 12);
        float4 a0 = p0[0], b0 = p0[1], c0 = p0[2];
        g0.x += a0.x; g0.y += a0.y; g0.z += a0.z; g0.w += a0.w;
        g1.x += b0.x; g1.y += b0.y; g1.z += b0.z; g1.w += b0.w;
        g8 += c0.x;
      }
      const float4* sn = (const float4*)(s_pad + (size_t)node * 12);
      float4 d0 = sn[0], d1 = sn[1], d2 = sn[2];
      float gg[9] = {g0.x, g0.y, g0.z, g0.w, g1.x, g1.y, g1.z, g1.w, g8};
      float sd[9] = {d0.x, d0.y, d0.z, d0.w, d1.x, d1.y, d1.z, d1.w, d2.x};
#pragma unroll
      for (int i = 0; i < 9; ++i)
#pragma unroll
        for (int jj = 0; jj < 9; ++jj) acc[i * 9 + jj] = fmaf(gg[i], sd[jj], acc[i * 9 + jj]);
    }

#pragma unroll
    for (int i = 0; i < 81; ++i) {
#pragma unroll
      for (int off = 32; off > 0; off >>= 1) acc[i] += __shfl_xor(acc[i], off, 64);
    }
    float* wsum = smem;  // reuse, 4*81 floats
    if (lane == 0) {
#pragma unroll
      for (int i = 0; i < 81; ++i) wsum[wave * 81 + i] = acc[i];
    }
    __syncthreads();
    if (t < 81) atomAddG(&glob[G_OA + t], wsum[t] + wsum[81 + t] + wsum[162 + t] + wsum[243 + t]);
  }
}

// ---- epilogue ----------------------------------------------------------

__global__ __launch_bounds__(128) void k_final(const float* __restrict__ glob, float* __restrict__ out) {
  const float* xp = glob + G_XP;
  const float* oa = glob + G_OA;
  const float* ssm = glob + G_SS;
  const float* den = glob + G_DEN;
  int t = threadIdx.x;
  __shared__ float red[128];

  for (int k = 0; k < 9; ++k) {
    float v = xp[k * 128 + t];
    red[t] = v;
    __syncthreads();
    for (int s2 = 64; s2 > 0; s2 >>= 1) {
      if (t < s2) red[t] = fmaxf(red[t], red[t + s2]);
      __syncthreads();
    }
    float m = red[0];
    __syncthreads();
    red[t] = expf(v - m);
    __syncthreads();
    for (int s2 = 64; s2 > 0; s2 >>= 1) {
      if (t < s2) red[t] += red[t + s2];
      __syncthreads();
    }
    float lz = logf(red[0]) + m;
    __syncthreads();
    out[k * 128 + t] = v - lz;
  }

  if (t == 0) {
    float num = 0.f;
    for (int q = 0; q < 9; ++q) num += oa[q * 9 + q];
    out[1152] = -(num / (den[0] + 1e-15f));

    float fn = 0.f;
    for (int i = 0; i < 81; ++i) fn += ssm[i] * ssm[i];
    float rfn = 1.0f / sqrtf(fn);
    float osum = 0.f;
    for (int i = 0; i < 9; ++i)
      for (int j = 0; j < 9; ++j) {
        float v = ssm[i * 9 + j] * rfn - ((i == j) ? (1.0f / 3.0f) : 0.f);
        osum += v * v;
      }
    out[1153] = sqrtf(osum);
  }

  __shared__ float dsh[9];
  if (t < 9) {
    float d = 0.f;
    for (int j = 0; j < 9; ++j)
      if (j != t) d += oa[t * 9 + j];
    dsh[t] = 1.0f / sqrtf(d + 1e-15f);
  }
  __syncthreads();
  if (t < 81) {
    int i = t / 9, j = t % 9;
    out[901154 + t] = (i == j) ? 0.f : dsh[i] * oa[t] * dsh[j];
  }
}

extern "C" void kernel_launch(void* const* d_in, const int* in_sizes, int n_in,
                              void* d_out, int out_size, void* d_ws, size_t ws_size,
                              hipStream_t stream) {
  const float* x = (const float*)d_in[0];
  const int* ei = (const int*)d_in[1];
  const float* W1 = (const float*)d_in[3];
  const float* b1 = (const float*)d_in[4];
  const float* Wp = (const float*)d_in[5];
  const float* bp = (const float*)d_in[6];
  float* out = (float*)d_out;

  // ws: deg_i[NN] | glob[1315] | rowptr[NN] | cursor[NN] | csr[NE] | dinv[NN] |
  //     s_pad[NN*12] | bsum[NB] | agg[NN*64] | h_glob[NN*128]
  int* deg_i = (int*)d_ws;
  float* glob = (float*)d_ws + NN;
  int* rowptr = (int*)d_ws + NN + 1315;
  int* cursor = rowptr + NN;
  int* csr = cursor + NN;
  float* dinv = (float*)(csr + NE);
  float* s_pad = dinv + NN;
  int* bsum = (int*)(s_pad + (size_t)NN * 12);
  float* agg = (float*)(bsum + NB + 2);
  float* h_glob = agg + (size_t)NN * INC;

  hipMemsetAsync(d_ws, 0, (size_t)(NN + 1315) * sizeof(float), stream);

  const int* src = ei;
  const int* dst = ei + NE;

  hipLaunchKernelGGL(k_deg, dim3(1024), dim3(256), 0, stream, dst, deg_i);
  hipLaunchKernelGGL(k_bsum, dim3(NB), dim3(256), 0, stream, deg_i, bsum);
  hipLaunchKernelGGL(k_write, dim3(NB), dim3(256), 0, stream, deg_i, bsum, rowptr, cursor, dinv);
  hipLaunchKernelGGL(k_fill, dim3(2048), dim3(256), 0, stream, src, dst, cursor, csr);
  hipLaunchKernelGGL(k_gather, dim3(6250), dim3(256), 0, stream, rowptr, deg_i, csr, x, dinv, agg);
  hipLaunchKernelGGL(k_mlpA, dim3((NN + 127) / 128), dim3(128), 0, stream, agg,
                     W1, b1, Wp, bp, out + 1154, s_pad, h_glob);
  hipLaunchKernelGGL(k_post, dim3(512), dim3(256), 0, stream, h_glob, s_pad, deg_i,
                     rowptr, csr, glob);
  hipLaunchKernelGGL(k_final, dim3(1), dim3(128), 0, stream, glob, out);
}